// Round 3
// baseline (415.685 us; speedup 1.0000x reference)
//
#include <hip/hip_runtime.h>

#define NCH   96
#define RF    25
#define HALF  12
#define HW    55
#define PLANE (HW * HW)        // 3025
#define NPIX  (128 * PLANE)    // 387200 pixels total
#define CAP   32               // max compact taps per channel; dense fallback beyond
#define MAXA  4                // max active channels per 48-ch half on fast path
#define NGRP  12               // float4 groups per half (48 ch)

// d_ws layout:
//   int   counts[NCH]            @ 0        (384 B)
//   int   tap_off[NCH][CAP]      @ 384      (12288 B)  packed (dy<<8)|dx
//   float tap_w [NCH][CAP]       @ 12672    (12288 B)
//   int   meta[64]               @ 24960
//     [0] flag (0 fast / 999 fallback)   [1][2] na per half
//     [3..6] h0 active ch   [7..10] h1 active ch
//     [11] ngi   [12..35] inactive GLOBAL float4-group ids (no active channel)
//     [36][37] ndg per half   [38..49] h0 deferred local groups  [50..61] h1
#define WS_META_OFF (NCH * 4 + NCH * CAP * 4 * 2)

__global__ __launch_bounds__(1024) void prep_all(
        const float* __restrict__ kern, int* __restrict__ counts,
        int* __restrict__ tap_off, float* __restrict__ tap_w,
        int* __restrict__ meta) {
    __shared__ int scnt[NCH];
    const int wave = threadIdx.x >> 6;
    const int lane = threadIdx.x & 63;
    for (int c = wave; c < NCH; c += 16) {
        const float* kc = kern + c * (RF * RF);
        int base = 0;
        for (int seg = 0; seg < RF * RF; seg += 64) {
            const int i = seg + lane;
            const float w = (i < RF * RF) ? kc[i] : 0.0f;
            const unsigned long long m = __ballot(w != 0.0f);
            const int pos = base + __popcll(m & ((1ull << lane) - 1ull));
            if (w != 0.0f && pos < CAP) {
                const int dy = i / RF, dx = i - dy * RF;
                tap_off[c * CAP + pos] = (dy << 8) | dx;
                tap_w[c * CAP + pos]   = w;
            }
            base += __popcll(m);
        }
        if (lane == 0) { counts[c] = base; scnt[c] = base; }
    }
    __syncthreads();
    if (threadIdx.x == 0) {
        int na[2] = {0, 0};
        bool fallback = false;
        for (int ch = 0; ch < NCH; ++ch) {
            if (scnt[ch] > 0) {
                if (scnt[ch] > CAP) fallback = true;
                const int h = ch / 48;
                if (na[h] < MAXA) meta[3 + h * MAXA + na[h]] = ch;
                ++na[h];
            }
        }
        if (na[0] > MAXA || na[1] > MAXA) fallback = true;
        meta[0] = fallback ? 999 : 0;
        meta[1] = na[0] < MAXA ? na[0] : MAXA;
        meta[2] = na[1] < MAXA ? na[1] : MAXA;
        for (int h = 0; h < 2; ++h)
            for (int i = na[h] < MAXA ? na[h] : MAXA; i < MAXA; ++i)
                meta[3 + h * MAXA + i] = 0;
        // sector classification: deferred (has active ch) vs pure-copy
        int ngi = 0;
        for (int h = 0; h < 2; ++h) {
            int nd = 0;
            for (int s = 0; s < 3; ++s) {
                bool act = false;
                for (int c = s * 16; c < s * 16 + 16; ++c)
                    act |= (scnt[h * 48 + c] > 0);
                if (act) { for (int g = s * 4; g < s * 4 + 4; ++g)
                               meta[38 + h * 12 + nd++] = g; }
                else     { for (int g = s * 4; g < s * 4 + 4; ++g)
                               meta[12 + ngi++] = h * NGRP + g; }
            }
            meta[36 + h] = nd;
        }
        meta[11] = ngi;
    }
}

__device__ __forceinline__ float conv_tap(const float (*shp)[56],
        const int* __restrict__ toffA, const float* __restrict__ twA,
        int cnt, int r, int col) {
    float acc = 0.0f;
    for (int t = 0; t < cnt; ++t) {
        const int off = toffA[t];
        const float w = twA[t];
        const int yy = r   + (off >> 8)  - HALF;
        const int xx = col + (off & 255) - HALF;
        const bool ok = ((unsigned)yy < (unsigned)HW) &
                        ((unsigned)xx < (unsigned)HW);
        const int yc = min(max(yy, 0), HW - 1);
        const int xc = min(max(xx, 0), HW - 1);
        const float vv = shp[yc][xc];
        acc += ok ? w * vv : 0.0f;
    }
    return acc;
}

// Grid 512 = 256 "active" blocks (b<256: image n=b>>1, half h=b&1, deferred
// sectors only, ~50 KB LDS) + 256 "copy" blocks (grid-stride over sectors
// with no active channel, LDS-idle). 2 blocks/CU -> 32 waves: copy stream
// hides the active blocks' barrier + latency stalls. Every 64 B output
// sector is written fully by exactly one wave-store group (no HBM RMW).
__global__ __launch_bounds__(1024, 8) void contour_split(
        const float* __restrict__ x, const float* __restrict__ kern,
        const int* __restrict__ counts, const int* __restrict__ tap_off,
        const float* __restrict__ tap_w, const int* __restrict__ meta,
        float* __restrict__ out) {
    __shared__ float sh[MAXA][HW][56];     // 49,280 B
    __shared__ float tw[MAXA][CAP];
    __shared__ int   toff[MAXA][CAP];
    __shared__ int   tcnt[MAXA];
    __shared__ signed char c2l[48];
    __shared__ int   dgS[12];
    __shared__ int   glS[24];
    __shared__ int   ndgS, flagS;

    const int tid = threadIdx.x;
    const int b   = blockIdx.x;

    if (tid == 0) flagS = meta[0];
    __syncthreads();
    const bool fast = (flagS != 999);

    if (b >= 256) {
        // ================= COPY ROLE =================
        if (!fast) return;                 // fallback: active blocks do all
        if (tid == 0) ndgS = meta[11];     // reuse ndgS as ngi
        if (tid < 24) glS[tid] = meta[12 + tid];
        __syncthreads();
        const int ngi = ndgS;
        if (ngi == 0) return;
        const int S    = 256 * 1024;
        const int gt   = (b - 256) * 1024 + tid;
        const int cols = S / ngi;          // pixel-columns per group
        if (gt >= cols * ngi) return;
        const int j = gt % ngi;
        const int g = glS[j];
        const float4* xs4 = (const float4*)x;
        float4*       os4 = (float4*)out;
        #pragma unroll 8
        for (int p = gt / ngi; p < NPIX; p += cols) {
            const int fi = p * 24 + g;
            os4[fi] = xs4[fi];             // full-sector coverage via 4 lanes
        }
        return;
    }

    // ================= ACTIVE ROLE =================
    const int n = b >> 1;
    const int h = b & 1;
    const float* xn = x   + (size_t)n * (PLANE * NCH);
    float*       on = out + (size_t)n * (PLANE * NCH);

    if (fast) {
        const int na = meta[1 + h];
        if (tid < 48) c2l[tid] = -1;
        if (tid == 0) ndgS = meta[36 + h];
        if (tid >= 128 && tid < 140) dgS[tid - 128] = meta[38 + h * 12 + (tid - 128)];
        __syncthreads();
        if (tid < na) {
            const int c = meta[3 + h * MAXA + tid];
            tcnt[tid] = counts[c];
            c2l[c - h * 48] = (signed char)tid;
        }
        if (tid >= 64 && tid < 64 + MAXA * CAP) {
            const int a = (tid - 64) / CAP, t = (tid - 64) % CAP;
            const int c = (a < na) ? meta[3 + h * MAXA + a] : h * 48;
            toff[a][t] = tap_off[c * CAP + t];
            tw[a][t]   = tap_w[c * CAP + t];
        }
        __syncthreads();

        const int ndg = ndgS;
        if (ndg == 0) return;
        const int pstep = 1024 / ndg;      // ndg in {4,8} -> 256/128
        const bool on_duty = (tid < pstep * ndg);

        int g = 0, a0 = -1, a1 = -1, a2 = -1, a3 = -1, pslot = 0;
        if (on_duty) {
            const int gslot = tid % ndg;
            pslot = tid / ndg;
            g = dgS[gslot];
            const int lc = g * 4;
            a0 = c2l[lc + 0]; a1 = c2l[lc + 1];
            a2 = c2l[lc + 2]; a3 = c2l[lc + 3];
        }
        const int fbase = h * NGRP + g;
        const float4* xs = (const float4*)xn;
        float4*       os = (float4*)on;

        // ---- sweep 1: stream deferred sectors, extract actives to LDS ----
        if (on_duty) {
            #pragma unroll 4
            for (int p = pslot; p < PLANE; p += pstep) {
                const float4 v = xs[p * 24 + fbase];
                const int r = p / HW, col = p - r * HW;
                if (a0 >= 0) sh[a0][r][col] = v.x;
                if (a1 >= 0) sh[a1][r][col] = v.y;
                if (a2 >= 0) sh[a2][r][col] = v.z;
                if (a3 >= 0) sh[a3][r][col] = v.w;
            }
        }
        __syncthreads();

        // ---- sweep 2: re-read (L2/L3-hot), fuse conv from sh, single write ----
        if (on_duty) {
            const int cnt0 = (a0 >= 0) ? tcnt[a0] : 0;
            const int cnt1 = (a1 >= 0) ? tcnt[a1] : 0;
            const int cnt2 = (a2 >= 0) ? tcnt[a2] : 0;
            const int cnt3 = (a3 >= 0) ? tcnt[a3] : 0;
            #pragma unroll 2
            for (int p = pslot; p < PLANE; p += pstep) {
                const int fi = p * 24 + fbase;
                float4 v = xs[fi];
                const int r = p / HW, col = p - r * HW;
                if (a0 >= 0) v.x += conv_tap(sh[a0], toff[a0], tw[a0], cnt0, r, col);
                if (a1 >= 0) v.y += conv_tap(sh[a1], toff[a1], tw[a1], cnt1, r, col);
                if (a2 >= 0) v.z += conv_tap(sh[a2], toff[a2], tw[a2], cnt2, r, col);
                if (a3 >= 0) v.w += conv_tap(sh[a3], toff[a3], tw[a3], cnt3, r, col);
                os[fi] = v;                // full coverage, no RMW
            }
        }
    } else {
        // ---- generic fallback (never taken for the reference mask) ----
        const float4* xs = (const float4*)xn;
        float4*       os = (float4*)on;
        for (int idx = tid; idx < PLANE * NGRP; idx += 1024) {
            const int px = idx / NGRP;
            const int gg = idx - px * NGRP;
            const int r  = px / HW, col = px - r * HW;
            const int fi = px * 24 + h * NGRP + gg;
            const float4 xv = xs[fi];
            float acc[4] = {xv.x, xv.y, xv.z, xv.w};
            for (int kk = 0; kk < 4; ++kk) {
                const int c = h * 48 + gg * 4 + kk;
                const int cnt = counts[c];
                if (cnt == 0) continue;
                float aa = 0.0f;
                if (cnt <= CAP) {
                    for (int t = 0; t < cnt; ++t) {
                        const int off = tap_off[c * CAP + t];
                        const float w = tap_w[c * CAP + t];
                        const int yy = r   + (off >> 8)  - HALF;
                        const int xx = col + (off & 255) - HALF;
                        if ((unsigned)yy < (unsigned)HW &&
                            (unsigned)xx < (unsigned)HW)
                            aa += w * xn[(size_t)(yy * HW + xx) * NCH + c];
                    }
                } else {
                    for (int dy = 0; dy < RF; ++dy)
                        for (int dx = 0; dx < RF; ++dx) {
                            const float w = kern[(c * RF + dy) * RF + dx];
                            if (w == 0.0f) continue;
                            const int yy = r   + dy - HALF;
                            const int xx = col + dx - HALF;
                            if ((unsigned)yy < (unsigned)HW &&
                                (unsigned)xx < (unsigned)HW)
                                aa += w * xn[(size_t)(yy * HW + xx) * NCH + c];
                        }
                }
                acc[kk] += aa;
            }
            os[fi] = make_float4(acc[0], acc[1], acc[2], acc[3]);
        }
    }
}

extern "C" void kernel_launch(void* const* d_in, const int* in_sizes, int n_in,
                              void* d_out, int out_size, void* d_ws, size_t ws_size,
                              hipStream_t stream) {
    const float* x    = (const float*)d_in[0];
    const float* kern = (const float*)d_in[1];
    float* out = (float*)d_out;

    int*   counts  = (int*)d_ws;
    int*   tap_off = (int*)((char*)d_ws + NCH * 4);
    float* tap_w   = (float*)((char*)d_ws + NCH * 4 + NCH * CAP * 4);
    int*   meta    = (int*)((char*)d_ws + WS_META_OFF);

    prep_all<<<1, 1024, 0, stream>>>(kern, counts, tap_off, tap_w, meta);

    // 256 active blocks (image x sector-aligned channel-half) + 256 copy
    // blocks (inactive sectors) -> 2 blocks/CU, copy stream hides stalls.
    contour_split<<<512, 1024, 0, stream>>>(x, kern, counts, tap_off, tap_w, meta, out);
}

// Round 5
// 342.674 us; speedup vs baseline: 1.2131x; 1.2131x over previous
//
#include <hip/hip_runtime.h>

#define NCH   96
#define RF    25
#define HALF  12
#define HW    55
#define PLANE (HW * HW)        // 3025
#define NPIX  (128 * PLANE)    // 387200 pixels total
#define CAP   32               // max compact taps per channel; dense fallback beyond
#define MAXA  4                // max active channels per 48-ch half on fast path
#define NGRP  12               // float4 groups per half (48 ch)

// meta layout (ints):
//  [0] flag (0 fast / 999 fallback)   [1][2] na per half (capped at MAXA)
//  [3..6] h0 active ch   [7..10] h1 active ch
//  [11..34] per-GLOBAL-group packed A map (4 bytes, 0xFF = inactive lane)
//  [40+h*16] nag[h]; then pairs {group id, packed local-a map} x nag
#define M_G2A 11
#define M_HG  40

// d_ws layout:
//   int   counts[NCH]            @ 0
//   int   tap_off[NCH][CAP]      @ 384      packed (dy<<8)|dx
//   float tap_w [NCH][CAP]       @ 12672
//   int   meta[..]               @ 24960
//   float latg[8][NPIX]          @ 32768    (12.39 MB, fast path only)
#define WS_META_OFF (NCH * 4 + NCH * CAP * 4 * 2)
#define WS_LAT_OFF  32768
#define WS_NEED     (WS_LAT_OFF + 8u * NPIX * 4u)

typedef float f32x4 __attribute__((ext_vector_type(4)));

__global__ __launch_bounds__(1024) void prep_all(
        const float* __restrict__ kern, int* __restrict__ counts,
        int* __restrict__ tap_off, float* __restrict__ tap_w,
        int* __restrict__ meta) {
    __shared__ int scnt[NCH];
    const int wave = threadIdx.x >> 6;
    const int lane = threadIdx.x & 63;
    for (int c = wave; c < NCH; c += 16) {
        const float* kc = kern + c * (RF * RF);
        int base = 0;
        for (int seg = 0; seg < RF * RF; seg += 64) {
            const int i = seg + lane;
            const float w = (i < RF * RF) ? kc[i] : 0.0f;
            const unsigned long long m = __ballot(w != 0.0f);
            const int pos = base + __popcll(m & ((1ull << lane) - 1ull));
            if (w != 0.0f && pos < CAP) {
                const int dy = i / RF, dx = i - dy * RF;
                tap_off[c * CAP + pos] = (dy << 8) | dx;
                tap_w[c * CAP + pos]   = w;
            }
            base += __popcll(m);
        }
        if (lane == 0) { counts[c] = base; scnt[c] = base; }
    }
    __syncthreads();
    if (threadIdx.x == 0) {
        int na[2] = {0, 0};
        int Aof[NCH];
        int Atot = 0;
        bool fallback = false;
        for (int ch = 0; ch < NCH; ++ch) {
            if (scnt[ch] > 0) {
                if (scnt[ch] > CAP) fallback = true;
                const int h = ch / 48;
                if (na[h] < MAXA) meta[3 + h * MAXA + na[h]] = ch;
                ++na[h];
                Aof[ch] = Atot++;
            } else Aof[ch] = -1;
        }
        if (na[0] > MAXA || na[1] > MAXA) fallback = true;
        meta[0] = fallback ? 999 : 0;
        const int na0 = na[0] < MAXA ? na[0] : MAXA;
        const int na1 = na[1] < MAXA ? na[1] : MAXA;
        meta[1] = na0; meta[2] = na1;
        for (int h = 0; h < 2; ++h)
            for (int i = (h ? na1 : na0); i < MAXA; ++i)
                meta[3 + h * MAXA + i] = 0;
        // per-global-group packed A map (for stream_stage)
        for (int g = 0; g < 24; ++g) {
            int pk = 0;
            for (int j = 0; j < 4; ++j) {
                const int c = g * 4 + j;
                const int a = (scnt[c] > 0) ? Aof[c] : -1;
                pk |= ((a < 0 ? 0xFF : a) & 0xFF) << (8 * j);
            }
            meta[M_G2A + g] = pk;
        }
        // per-half gather lists (for conv_stage); local a = A - base
        for (int h = 0; h < 2; ++h) {
            const int base = h ? na0 : 0;
            int nag = 0;
            for (int g = h * NGRP; g < h * NGRP + NGRP; ++g) {
                int pk = 0; bool any = false;
                for (int j = 0; j < 4; ++j) {
                    const int c = g * 4 + j;
                    int la = -1;
                    if (scnt[c] > 0) { la = Aof[c] - base; any = true; }
                    pk |= ((la < 0 ? 0xFF : la) & 0xFF) << (8 * j);
                }
                if (any && nag < 6) {
                    meta[M_HG + h * 16 + 1 + 2 * nag] = g;
                    meta[M_HG + h * 16 + 2 + 2 * nag] = pk;
                    ++nag;
                }
            }
            meta[M_HG + h * 16] = nag;
        }
    }
}

__device__ __forceinline__ float conv_tap(const float (*shp)[56],
        const int* __restrict__ toffA, const float* __restrict__ twA,
        int cnt, int r, int col) {
    float acc = 0.0f;
    for (int t = 0; t < cnt; ++t) {
        const int off = toffA[t];
        const float w = twA[t];
        const int yy = r   + (off >> 8)  - HALF;
        const int xx = col + (off & 255) - HALF;
        const bool ok = ((unsigned)yy < (unsigned)HW) &
                        ((unsigned)xx < (unsigned)HW);
        const int yc = min(max(yy, 0), HW - 1);
        const int xc = min(max(xx, 0), HW - 1);
        const float vv = shp[yc][xc];
        acc += ok ? w * vv : 0.0f;
    }
    return acc;
}

// Stage 1: block = (image, channel-half). Gather only the <=4 active
// float4 groups per pixel (sector footprint 192 B/px), conv from LDS
// (full plane, NO halo), write compact lat planes to workspace.
// Normal (caching) loads on purpose: the touched sectors stay in L3 and
// serve stage 2's re-read for free.
__global__ __launch_bounds__(1024, 2) void conv_stage(
        const float* __restrict__ x, const int* __restrict__ counts,
        const int* __restrict__ tap_off, const float* __restrict__ tap_w,
        const int* __restrict__ meta, float* __restrict__ latg) {
    __shared__ float sh[MAXA][HW][56];
    __shared__ float tw[MAXA][CAP];
    __shared__ int   toff[MAXA][CAP];
    __shared__ int   tcnt[MAXA];
    __shared__ int   gidS[6], gmapS[6];

    if (meta[0] == 999) return;          // dense fallback handled in stage 2
    const int tid = threadIdx.x;
    const int b   = blockIdx.x;
    const int n   = b >> 1;
    const int h   = b & 1;
    const int na  = meta[1 + h];
    const int nag = meta[M_HG + h * 16];
    if (na == 0 || nag == 0) return;

    if (tid < 6) {
        gidS[tid]  = meta[M_HG + h * 16 + 1 + 2 * tid];
        gmapS[tid] = meta[M_HG + h * 16 + 2 + 2 * tid];
    }
    if (tid < MAXA)
        tcnt[tid] = (tid < na) ? counts[meta[3 + h * MAXA + tid]] : 0;
    if (tid >= 64 && tid < 64 + MAXA * CAP) {
        const int a = (tid - 64) / CAP, t = (tid - 64) % CAP;
        const int c = meta[3 + h * MAXA + ((a < na) ? a : 0)];
        toff[a][t] = tap_off[c * CAP + t];
        tw[a][t]   = tap_w[c * CAP + t];
    }
    __syncthreads();

    const float4* xs = (const float4*)(x + (size_t)n * (PLANE * NCH));

    // gather: idx -> (pixel, group-slot); in-register extraction to LDS
    const int totG = PLANE * nag;
    for (int idx = tid; idx < totG; idx += 1024) {
        const int p    = idx / nag;
        const int slot = idx - p * nag;
        const int g  = gidS[slot];
        const int mp = gmapS[slot];
        const float4 v = xs[p * 24 + g];
        const int r = p / HW, col = p - r * HW;
        const int a0 = (signed char)mp,         a1 = (signed char)(mp >> 8);
        const int a2 = (signed char)(mp >> 16), a3 = (signed char)(mp >> 24);
        if (a0 >= 0) sh[a0][r][col] = v.x;
        if (a1 >= 0) sh[a1][r][col] = v.y;
        if (a2 >= 0) sh[a2][r][col] = v.z;
        if (a3 >= 0) sh[a3][r][col] = v.w;
    }
    __syncthreads();

    // conv -> compact lat planes (coalesced 4B stores)
    const int base = h ? meta[1] : 0;
    const int totC = na * PLANE;
    for (int idx = tid; idx < totC; idx += 1024) {
        const int a = idx / PLANE, p = idx - a * PLANE;
        const int r = p / HW, col = p - r * HW;
        const float acc = conv_tap(sh[a], toff[a], tw[a], tcnt[a], r, col);
        latg[(size_t)(base + a) * NPIX + n * PLANE + p] = acc;
    }
}

// Stage 2: pure stream. thread -> fixed global group g = tid%24 (1008
// threads cover 42 pixel-records contiguously per block-iteration).
// Nontemporal load/store: the streams don't allocate in L2/L3, so
// conv_stage's L3-resident active sectors survive and serve the lat-side
// re-reads. Every 16B of out written exactly once, fully -> no HBM RMW.
__global__ __launch_bounds__(1024, 2) void stream_stage(
        const float* __restrict__ x, const float* __restrict__ kern,
        const int* __restrict__ counts, const int* __restrict__ tap_off,
        const float* __restrict__ tap_w, const int* __restrict__ meta,
        const float* __restrict__ latg, float* __restrict__ out, int force_dense) {
    const int tid = threadIdx.x;
    if (meta[0] != 999 && !force_dense) {
        __shared__ int g2a[24];
        if (tid < 24) g2a[tid] = meta[M_G2A + tid];
        __syncthreads();
        if (tid >= 1008) return;
        const int g     = tid % 24;
        const int gslot = tid / 24;
        const int pk = g2a[g];
        const int a0 = (signed char)pk,         a1 = (signed char)(pk >> 8);
        const int a2 = (signed char)(pk >> 16), a3 = (signed char)(pk >> 24);
        const f32x4* xs = (const f32x4*)x;
        f32x4*       os = (f32x4*)out;
        const int stride = gridDim.x * 42;
        #pragma unroll 4
        for (int gp = blockIdx.x * 42 + gslot; gp < NPIX; gp += stride) {
            const size_t fi = (size_t)gp * 24 + g;
            f32x4 v = __builtin_nontemporal_load(&xs[fi]);
            if (a0 >= 0) v.x += latg[(size_t)a0 * NPIX + gp];
            if (a1 >= 0) v.y += latg[(size_t)a1 * NPIX + gp];
            if (a2 >= 0) v.z += latg[(size_t)a2 * NPIX + gp];
            if (a3 >= 0) v.w += latg[(size_t)a3 * NPIX + gp];
            __builtin_nontemporal_store(v, &os[fi]);
        }
    } else {
        // generic tap-table fallback over all (pixel, group) float4s
        const float4* xs4 = (const float4*)x;
        float4*       os4 = (float4*)out;
        const long long tot = (long long)NPIX * 24;
        for (long long ii = (long long)blockIdx.x * 1024 + tid; ii < tot;
             ii += (long long)gridDim.x * 1024) {
            const int gp = (int)(ii / 24);
            const int gg = (int)(ii - (long long)gp * 24);
            const int n  = gp / PLANE, p = gp - n * PLANE;
            const int r  = p / HW, col = p - r * HW;
            const float* xn = x + (size_t)n * (PLANE * NCH);
            const float4 xv = xs4[ii];
            float acc[4] = {xv.x, xv.y, xv.z, xv.w};
            for (int kk = 0; kk < 4; ++kk) {
                const int c = gg * 4 + kk;
                const int cnt = counts[c];
                if (cnt == 0) continue;
                float aa = 0.0f;
                if (cnt <= CAP) {
                    for (int t = 0; t < cnt; ++t) {
                        const int off = tap_off[c * CAP + t];
                        const float w = tap_w[c * CAP + t];
                        const int yy = r   + (off >> 8)  - HALF;
                        const int xx = col + (off & 255) - HALF;
                        if ((unsigned)yy < (unsigned)HW &&
                            (unsigned)xx < (unsigned)HW)
                            aa += w * xn[(size_t)(yy * HW + xx) * NCH + c];
                    }
                } else {
                    for (int dy = 0; dy < RF; ++dy)
                        for (int dx = 0; dx < RF; ++dx) {
                            const float w = kern[(c * RF + dy) * RF + dx];
                            if (w == 0.0f) continue;
                            const int yy = r   + dy - HALF;
                            const int xx = col + dx - HALF;
                            if ((unsigned)yy < (unsigned)HW &&
                                (unsigned)xx < (unsigned)HW)
                                aa += w * xn[(size_t)(yy * HW + xx) * NCH + c];
                        }
                }
                acc[kk] += aa;
            }
            os4[ii] = make_float4(acc[0], acc[1], acc[2], acc[3]);
        }
    }
}

extern "C" void kernel_launch(void* const* d_in, const int* in_sizes, int n_in,
                              void* d_out, int out_size, void* d_ws, size_t ws_size,
                              hipStream_t stream) {
    const float* x    = (const float*)d_in[0];
    const float* kern = (const float*)d_in[1];
    float* out = (float*)d_out;

    int*   counts  = (int*)d_ws;
    int*   tap_off = (int*)((char*)d_ws + NCH * 4);
    float* tap_w   = (float*)((char*)d_ws + NCH * 4 + NCH * CAP * 4);
    int*   meta    = (int*)((char*)d_ws + WS_META_OFF);
    float* latg    = (float*)((char*)d_ws + WS_LAT_OFF);

    prep_all<<<1, 1024, 0, stream>>>(kern, counts, tap_off, tap_w, meta);

    const int force_dense = (ws_size < (size_t)WS_NEED) ? 1 : 0;
    if (!force_dense)
        conv_stage<<<256, 1024, 0, stream>>>(x, counts, tap_off, tap_w, meta, latg);
    stream_stage<<<2048, 1024, 0, stream>>>(x, kern, counts, tap_off, tap_w,
                                            meta, latg, out, force_dense);
}